// Round 18
// baseline (28.852 us; speedup 1.0000x reference)
//
#include <hip/hip_runtime.h>
#include <hip/hip_bf16.h>

#define N_PAIR 4096
#define N_ROW  8192
#define DIM    128
#define NX     8     // col-tiles swept per block

typedef __attribute__((ext_vector_type(4))) float f32x4;
typedef __attribute__((ext_vector_type(4))) int   i32x4;
typedef __attribute__((ext_vector_type(8))) int   i32x8;

__device__ inline float fast_exp2(float x) {
#if __has_builtin(__builtin_amdgcn_exp2f)
    return __builtin_amdgcn_exp2f(x);
#else
    float r; asm("v_exp_f32 %0, %1" : "=v"(r) : "v"(x)); return r;
#endif
}
__device__ inline float fast_log2(float x) {
#if __has_builtin(__builtin_amdgcn_logf)
    return __builtin_amdgcn_logf(x);
#else
    float r; asm("v_log_f32 %0, %1" : "=v"(r) : "v"(x)); return r;
#endif
}

// K1: interleave + L2-normalize, PRE-SCALED by sqrt(2/ln2) -> zh8 (e4m3):
//     MFMA yields K2E*s directly, epilogue mul disappears. Partner dot -> pd
//     (exact fp32); zero rowsum and out. One pair per wave.
__global__ __launch_bounds__(256) void k_prep(const float* __restrict__ zi,
                                              const float* __restrict__ zj,
                                              unsigned char* __restrict__ zh8,
                                              float* __restrict__ pd,
                                              float* __restrict__ rowsum,
                                              float* __restrict__ out) {
    const int wid  = threadIdx.x >> 6;
    const int lane = threadIdx.x & 63;
    const int k    = blockIdx.x * 4 + wid;
    float2 a = *(const float2*)&zi[k * DIM + lane * 2];
    float2 b = *(const float2*)&zj[k * DIM + lane * 2];
    float ssi = a.x * a.x + a.y * a.y;
    float ssj = b.x * b.x + b.y * b.y;
    float dot = a.x * b.x + a.y * b.y;
#pragma unroll
    for (int off = 1; off < 64; off <<= 1) {
        ssi += __shfl_xor(ssi, off);
        ssj += __shfl_xor(ssj, off);
        dot += __shfl_xor(dot, off);
    }
    const float SCL  = 1.6986436816458534f;   // sqrt(2/ln2)
    const float invi = rsqrtf(ssi), invj = rsqrtf(ssj);
    const float qi = invi * SCL, qj = invj * SCL;
    unsigned int pi = __builtin_amdgcn_cvt_pk_fp8_f32(a.x * qi, a.y * qi, 0, false);
    unsigned int pj = __builtin_amdgcn_cvt_pk_fp8_f32(b.x * qj, b.y * qj, 0, false);
    ((unsigned short*)zh8)[(2 * k)     * (DIM / 2) + lane] = (unsigned short)pi;
    ((unsigned short*)zh8)[(2 * k + 1) * (DIM / 2) + lane] = (unsigned short)pj;
    if (lane == 0) {
        pd[k] = dot * invi * invj;
        rowsum[2 * k]     = 0.f;
        rowsum[2 * k + 1] = 0.f;
        if (k == 0) out[0] = 0.f;
    }
}

// K2: full-matrix S' = Zh*Zh^T via MX-scaled fp8 MFMA (16x16x128, scales=1.0).
//     OCCUPANCY-JUMP layout: wave = 32 rows x 32 cols (a[2]+accT[2][2] ~ 60
//     VGPR), launch_bounds(512,8) -> 8 waves/SIMD, 32 waves/CU, 4 blocks/CU.
//     Block = 8 waves = 64 rows x 128 cols; B-tile (16 KB, 4 col-slices)
//     staged cooperatively (wave (wr,wc) stages half of slice wc), double-
//     buffered; one vmcnt(0)+barrier per tile. XOR-swizzled source/read
//     involution as before. Transposed mfma(b,a) -> row lane-local rowsum.
__global__ __launch_bounds__(512, 8) void k_simsum(const unsigned char* __restrict__ zh8,
                                                   float* __restrict__ rowsum) {
    __shared__ unsigned char Bs[2][16384];          // dbuf: 4 slices x 4 KB
    __shared__ float rsum_lds[64];
    const int tid  = threadIdx.x;
    const int lane = tid & 63;
    const int wid  = tid >> 6;                      // 0..7
    const int wr   = wid >> 2, wc = wid & 3;        // 32-row strip / 32-col strip
    const int l15  = lane & 15, lhi = lane >> 4;
    const int by   = blockIdx.y;                    // 64-row strip, 0..127
    const int bx0  = blockIdx.x * NX;
    const int row0 = by * 64 + wr * 32;             // wave's A-row base

    if (tid < 64) rsum_lds[tid] = 0.f;

    // A fragments (whole K=128 per lane-chunk): a[m] = bytes [lhi*32, lhi*32+32)
    i32x8 a[2];
#pragma unroll
    for (int m = 0; m < 2; ++m) {
        const unsigned char* ap = &zh8[(row0 + m * 16 + l15) * DIM + lhi * 32];
        union { i32x4 h[2]; i32x8 v; } u;
        u.h[0] = *(const i32x4*)ap;
        u.h[1] = *(const i32x4*)(ap + 16);
        a[m] = u.v;
    }

    // cooperative stage: wave (wr,wc) stages local rows [wr*16, wr*16+16) of
    // col-slice wc (32 rows x 128B). dest lane-linear; source XOR-swizzled
    // g = (lane&7)^(lane>>3) == chunk ^ (row&7) on the read side (involution).
    auto stage = [&](int ct, int buf) {
#pragma unroll
        for (int i = 0; i < 2; ++i) {
            const int rl = wr * 16 + i * 8 + (lane >> 3);   // 0..31 slice row
            const int g  = (lane & 7) ^ (lane >> 3);
            const unsigned char* src = zh8 + (ct * 128 + wc * 32 + rl) * DIM + g * 16;
            __builtin_amdgcn_global_load_lds(
                (const __attribute__((address_space(1))) void*)src,
                (__attribute__((address_space(3))) void*)(&Bs[buf][wc * 4096 + wr * 2048 + i * 1024]),
                16, 0, 0);
        }
    };

    const int SC1 = 0x7F7F7F7F;                     // e8m0 scale = 1.0 (all bytes)
    float rs[2] = {0.f, 0.f};

    stage(bx0, 0);
    asm volatile("s_waitcnt vmcnt(0)" ::: "memory");
    __builtin_amdgcn_s_barrier();                   // staging + rsum_lds zero visible

    int cur = 0;
#pragma unroll 1
    for (int t = 0; t < NX; ++t) {
        if (t + 1 < NX) stage(bx0 + t + 1, cur ^ 1);   // prefetch into other buf
        const int bx = bx0 + t;
        // b[n]: 32 bytes of slice-local B-row (n*16+l15), chunks lhi*2, lhi*2+1
        i32x8 b[2];
#pragma unroll
        for (int n = 0; n < 2; ++n) {
            const int rowb = n * 16 + l15;
            const int base = wc * 4096 + rowb * 128;
            union { i32x4 h[2]; i32x8 v; } u;
            u.h[0] = *(const i32x4*)&Bs[cur][base + (((lhi * 2 + 0) ^ (l15 & 7)) << 4)];
            u.h[1] = *(const i32x4*)&Bs[cur][base + (((lhi * 2 + 1) ^ (l15 & 7)) << 4)];
            b[n] = u.v;
        }
        f32x4 accT[2][2];
        __builtin_amdgcn_s_setprio(1);
#pragma unroll
        for (int n = 0; n < 2; ++n)
#pragma unroll
            for (int m = 0; m < 2; ++m)
                accT[n][m] = __builtin_amdgcn_mfma_scale_f32_16x16x128_f8f6f4(
                    b[n], a[m], (f32x4){0.f, 0.f, 0.f, 0.f},
                    0, 0,              // cbsz/blgp: fp8 e4m3 both operands
                    0, SC1, 0, SC1);   // scales = 1.0
        __builtin_amdgcn_s_setprio(0);
        if (bx == (by >> 1)) {                       // tile contains the diagonal
            const int coff = (by & 1) * 64;          // diag column offset in tile
#pragma unroll
            for (int m = 0; m < 2; ++m) {
                const int rloc = wr * 32 + m * 16 + l15;
                float s0 = 0.f, s1 = 0.f;
#pragma unroll
                for (int n = 0; n < 2; ++n)
#pragma unroll
                    for (int r = 0; r < 4; ++r) {
                        const int cloc = wc * 32 + n * 16 + lhi * 4 + r;
                        float v = fast_exp2(accT[n][m][r]);
                        v = (cloc == coff + rloc) ? 0.f : v;
                        if (n == 0) s0 += v; else s1 += v;
                    }
                rs[m] += s0 + s1;
            }
        } else {
#pragma unroll
            for (int m = 0; m < 2; ++m) {
                float s0 = 0.f, s1 = 0.f;
#pragma unroll
                for (int n = 0; n < 2; ++n)
#pragma unroll
                    for (int r = 0; r < 4; ++r) {
                        float v = fast_exp2(accT[n][m][r]);
                        if (n == 0) s0 += v; else s1 += v;
                    }
                rs[m] += s0 + s1;
            }
        }
        if (t + 1 < NX) {
            asm volatile("s_waitcnt vmcnt(0)" ::: "memory");   // own staging landed
            __builtin_amdgcn_s_barrier();            // all waves staged + reads done
            cur ^= 1;
        }
    }

    // fold lhi groups -> lanes<16 hold per-row partials; wc-fold via LDS, then
    // one global atomic per row per block (64 total).
#pragma unroll
    for (int m = 0; m < 2; ++m) {
        rs[m] += __shfl_xor(rs[m], 16);
        rs[m] += __shfl_xor(rs[m], 32);
    }
    __syncthreads();                                 // reuse of rsum_lds is safe
    if (lane < 16) {
#pragma unroll
        for (int m = 0; m < 2; ++m)
            atomicAdd(&rsum_lds[wr * 32 + m * 16 + lane], rs[m]);
    }
    __syncthreads();
    if (tid < 64) atomicAdd(&rowsum[by * 64 + tid], rsum_lds[tid]);
}

// K3: 32 blocks x 256 thr; per-block pre-divided float atomic into out
//     (out zeroed by k_prep, stream-ordered; replay-deterministic).
__global__ __launch_bounds__(256) void k_loss(const float* __restrict__ rowsum,
                                              const float* __restrict__ pd,
                                              float* __restrict__ out) {
    const int tid  = threadIdx.x;
    const int lane = tid & 63;
    const int wid  = tid >> 6;
    const int i    = blockIdx.x * 256 + tid;        // 0..8191
    const float LN2 = 0.6931471805599453f;
    float local = fast_log2(rowsum[i]) * LN2 - 2.f * pd[i >> 1];
#pragma unroll
    for (int off = 1; off < 64; off <<= 1) local += __shfl_xor(local, off);
    __shared__ float wsum[4];
    if (lane == 0) wsum[wid] = local;
    __syncthreads();
    if (tid == 0)
        atomicAdd(out, (wsum[0] + wsum[1] + wsum[2] + wsum[3]) * (1.f / (float)N_ROW));
}

extern "C" void kernel_launch(void* const* d_in, const int* in_sizes, int n_in,
                              void* d_out, int out_size, void* d_ws, size_t ws_size,
                              hipStream_t stream) {
    const float* zi = (const float*)d_in[0];
    const float* zj = (const float*)d_in[1];
    char* ws = (char*)d_ws;
    unsigned char* zh8 = (unsigned char*)ws;                      // 1 MiB
    float* rowsum = (float*)(ws + 2 * 1024 * 1024);               // 32 KiB
    float* pd     = (float*)(ws + 2 * 1024 * 1024 + 32 * 1024);   // 16 KiB

    k_prep<<<N_PAIR / 4, 256, 0, stream>>>(zi, zj, zh8, pd, rowsum, (float*)d_out);
    dim3 grid(64 / NX, 128);
    k_simsum<<<grid, 512, 0, stream>>>(zh8, rowsum);
    k_loss<<<N_ROW / 256, 256, 0, stream>>>(rowsum, pd, (float*)d_out);
}

// Round 19
// 28.170 us; speedup vs baseline: 1.0242x; 1.0242x over previous
//
#include <hip/hip_runtime.h>
#include <hip/hip_bf16.h>

#define N_PAIR 4096
#define N_ROW  8192
#define DIM    128
#define NX     8     // col-tiles swept per block

typedef __attribute__((ext_vector_type(4))) float f32x4;
typedef __attribute__((ext_vector_type(4))) int   i32x4;
typedef __attribute__((ext_vector_type(8))) int   i32x8;

__device__ inline float fast_exp2(float x) {
#if __has_builtin(__builtin_amdgcn_exp2f)
    return __builtin_amdgcn_exp2f(x);
#else
    float r; asm("v_exp_f32 %0, %1" : "=v"(r) : "v"(x)); return r;
#endif
}
__device__ inline float fast_log2(float x) {
#if __has_builtin(__builtin_amdgcn_logf)
    return __builtin_amdgcn_logf(x);
#else
    float r; asm("v_log_f32 %0, %1" : "=v"(r) : "v"(x)); return r;
#endif
}

// K1: interleave + L2-normalize, PRE-SCALED by sqrt(2/ln2) -> zh8 (e4m3):
//     MFMA yields K2E*s directly, epilogue mul disappears. Partner dot -> pd
//     (exact fp32); zero rowsum and out. One pair per wave.
__global__ __launch_bounds__(256) void k_prep(const float* __restrict__ zi,
                                              const float* __restrict__ zj,
                                              unsigned char* __restrict__ zh8,
                                              float* __restrict__ pd,
                                              float* __restrict__ rowsum,
                                              float* __restrict__ out) {
    const int wid  = threadIdx.x >> 6;
    const int lane = threadIdx.x & 63;
    const int k    = blockIdx.x * 4 + wid;
    float2 a = *(const float2*)&zi[k * DIM + lane * 2];
    float2 b = *(const float2*)&zj[k * DIM + lane * 2];
    float ssi = a.x * a.x + a.y * a.y;
    float ssj = b.x * b.x + b.y * b.y;
    float dot = a.x * b.x + a.y * b.y;
#pragma unroll
    for (int off = 1; off < 64; off <<= 1) {
        ssi += __shfl_xor(ssi, off);
        ssj += __shfl_xor(ssj, off);
        dot += __shfl_xor(dot, off);
    }
    const float SCL  = 1.6986436816458534f;   // sqrt(2/ln2)
    const float invi = rsqrtf(ssi), invj = rsqrtf(ssj);
    const float qi = invi * SCL, qj = invj * SCL;
    unsigned int pi = __builtin_amdgcn_cvt_pk_fp8_f32(a.x * qi, a.y * qi, 0, false);
    unsigned int pj = __builtin_amdgcn_cvt_pk_fp8_f32(b.x * qj, b.y * qj, 0, false);
    ((unsigned short*)zh8)[(2 * k)     * (DIM / 2) + lane] = (unsigned short)pi;
    ((unsigned short*)zh8)[(2 * k + 1) * (DIM / 2) + lane] = (unsigned short)pj;
    if (lane == 0) {
        pd[k] = dot * invi * invj;
        rowsum[2 * k]     = 0.f;
        rowsum[2 * k + 1] = 0.f;
        if (k == 0) out[0] = 0.f;
    }
}

// K2: full-matrix S' = Zh*Zh^T via MX-scaled fp8 MFMA (16x16x128, scales=1.0).
//     8-waves/SIMD BARRIER-FREE: wave = 32 rows x 32 cols (~60 VGPR), private
//     4KB single-buffer staging with in-wave overlap: ds_reads of tile t retire
//     to regs (lgkmcnt 0) -> buffer is dead -> stage(t+1) issues BEFORE t's
//     MFMA/epilogue, overlapping staging with compute in one buffer.
//     launch_bounds(512,8): 4 blocks/CU, 32 waves/CU. Transposed mfma(b,a) ->
//     row lane-local rowsum. One barrier pair only (pre-loop zero, final fold).
__global__ __launch_bounds__(512, 8) void k_simsum(const unsigned char* __restrict__ zh8,
                                                   float* __restrict__ rowsum) {
    __shared__ unsigned char Bs[8 * 4096];          // per-wave: 1 buf x 4 KB
    __shared__ float rsum_lds[64];
    const int tid  = threadIdx.x;
    const int lane = tid & 63;
    const int wid  = tid >> 6;                      // 0..7
    const int wr   = wid >> 2, wc = wid & 3;        // 32-row strip / 32-col strip
    const int l15  = lane & 15, lhi = lane >> 4;
    const int by   = blockIdx.y;                    // 64-row strip, 0..127
    const int bx0  = blockIdx.x * NX;
    const int row0 = by * 64 + wr * 32;             // wave's A-row base
    const int wbase = wid * 4096;                   // this wave's LDS region

    if (tid < 64) rsum_lds[tid] = 0.f;
    __syncthreads();                                 // once, before the loop

    // A fragments (whole K=128 per lane-chunk): a[m] = bytes [lhi*32, lhi*32+32)
    i32x8 a[2];
#pragma unroll
    for (int m = 0; m < 2; ++m) {
        const unsigned char* ap = &zh8[(row0 + m * 16 + l15) * DIM + lhi * 32];
        union { i32x4 h[2]; i32x8 v; } u;
        u.h[0] = *(const i32x4*)ap;
        u.h[1] = *(const i32x4*)(ap + 16);
        a[m] = u.v;
    }

    // precomputed per-lane invariants (keep VGPR count low)
    const int rl      = lane >> 3;                   // staging row within 8-row group
    const int stg_off = (wc * 32 + rl) * DIM + (((lane & 7) ^ (rl & 7)) << 4);
    int rd_off[2][2];                                // ds_read byte offsets
#pragma unroll
    for (int n = 0; n < 2; ++n) {
        const int rowb = n * 16 + l15;
#pragma unroll
        for (int c = 0; c < 2; ++c)
            rd_off[n][c] = wbase + rowb * 128 + (((lhi * 2 + c) ^ (l15 & 7)) << 4);
    }

    // stage this wave's 32-row B-slice of col-tile ct into its private buffer.
    // dest lane-linear; source XOR-swizzled (involution with the read side).
    auto stage = [&](int ct) {
#pragma unroll
        for (int i = 0; i < 4; ++i) {
            const unsigned char* src = zh8 + ct * (128 * DIM) + stg_off + i * (8 * DIM);
            __builtin_amdgcn_global_load_lds(
                (const __attribute__((address_space(1))) void*)src,
                (__attribute__((address_space(3))) void*)(&Bs[wbase + i * 1024]),
                16, 0, 0);
        }
    };

    const int SC1 = 0x7F7F7F7F;                     // e8m0 scale = 1.0 (all bytes)
    float rs[2] = {0.f, 0.f};

    stage(bx0);
    asm volatile("s_waitcnt vmcnt(0)" ::: "memory");

#pragma unroll 1
    for (int t = 0; t < NX; ++t) {
        const int bx = bx0 + t;
        // b[n]: 32 bytes of slice-local B-row (n*16+l15)
        i32x8 b[2];
#pragma unroll
        for (int n = 0; n < 2; ++n) {
            union { i32x4 h[2]; i32x8 v; } u;
            u.h[0] = *(const i32x4*)&Bs[rd_off[n][0]];
            u.h[1] = *(const i32x4*)&Bs[rd_off[n][1]];
            b[n] = u.v;
        }
        // b regs hold tile t -> buffer is dead -> prefetch t+1 into same buffer
        asm volatile("s_waitcnt lgkmcnt(0)" ::: "memory");
        if (t + 1 < NX) stage(bx0 + t + 1);

        f32x4 accT[2][2];
        __builtin_amdgcn_s_setprio(1);
#pragma unroll
        for (int n = 0; n < 2; ++n)
#pragma unroll
            for (int m = 0; m < 2; ++m)
                accT[n][m] = __builtin_amdgcn_mfma_scale_f32_16x16x128_f8f6f4(
                    b[n], a[m], (f32x4){0.f, 0.f, 0.f, 0.f},
                    0, 0,              // cbsz/blgp: fp8 e4m3 both operands
                    0, SC1, 0, SC1);   // scales = 1.0
        __builtin_amdgcn_s_setprio(0);

        if (bx == (by >> 1)) {                       // tile contains the diagonal
            const int coff = (by & 1) * 64;          // diag column offset in tile
#pragma unroll
            for (int m = 0; m < 2; ++m) {
                const int rloc = wr * 32 + m * 16 + l15;
                float s0 = 0.f, s1 = 0.f;
#pragma unroll
                for (int n = 0; n < 2; ++n)
#pragma unroll
                    for (int r = 0; r < 4; ++r) {
                        const int cloc = wc * 32 + n * 16 + lhi * 4 + r;
                        float v = fast_exp2(accT[n][m][r]);
                        v = (cloc == coff + rloc) ? 0.f : v;
                        if (n == 0) s0 += v; else s1 += v;
                    }
                rs[m] += s0 + s1;
            }
        } else {
#pragma unroll
            for (int m = 0; m < 2; ++m) {
                float s0 = 0.f, s1 = 0.f;
#pragma unroll
                for (int n = 0; n < 2; ++n)
#pragma unroll
                    for (int r = 0; r < 4; ++r) {
                        float v = fast_exp2(accT[n][m][r]);
                        if (n == 0) s0 += v; else s1 += v;
                    }
                rs[m] += s0 + s1;
            }
        }
        if (t + 1 < NX)
            asm volatile("s_waitcnt vmcnt(0)" ::: "memory");   // own staging landed
    }

    // fold lhi groups -> lanes<16 hold per-row partials; fold waves via LDS,
    // then one global atomic per row per block (64 total).
#pragma unroll
    for (int m = 0; m < 2; ++m) {
        rs[m] += __shfl_xor(rs[m], 16);
        rs[m] += __shfl_xor(rs[m], 32);
    }
    if (lane < 16) {
#pragma unroll
        for (int m = 0; m < 2; ++m)
            atomicAdd(&rsum_lds[wr * 32 + m * 16 + lane], rs[m]);
    }
    __syncthreads();
    if (tid < 64) atomicAdd(&rowsum[by * 64 + tid], rsum_lds[tid]);
}

// K3: 32 blocks x 256 thr; per-block pre-divided float atomic into out
//     (out zeroed by k_prep, stream-ordered; replay-deterministic).
__global__ __launch_bounds__(256) void k_loss(const float* __restrict__ rowsum,
                                              const float* __restrict__ pd,
                                              float* __restrict__ out) {
    const int tid  = threadIdx.x;
    const int lane = tid & 63;
    const int wid  = tid >> 6;
    const int i    = blockIdx.x * 256 + tid;        // 0..8191
    const float LN2 = 0.6931471805599453f;
    float local = fast_log2(rowsum[i]) * LN2 - 2.f * pd[i >> 1];
#pragma unroll
    for (int off = 1; off < 64; off <<= 1) local += __shfl_xor(local, off);
    __shared__ float wsum[4];
    if (lane == 0) wsum[wid] = local;
    __syncthreads();
    if (tid == 0)
        atomicAdd(out, (wsum[0] + wsum[1] + wsum[2] + wsum[3]) * (1.f / (float)N_ROW));
}

extern "C" void kernel_launch(void* const* d_in, const int* in_sizes, int n_in,
                              void* d_out, int out_size, void* d_ws, size_t ws_size,
                              hipStream_t stream) {
    const float* zi = (const float*)d_in[0];
    const float* zj = (const float*)d_in[1];
    char* ws = (char*)d_ws;
    unsigned char* zh8 = (unsigned char*)ws;                      // 1 MiB
    float* rowsum = (float*)(ws + 2 * 1024 * 1024);               // 32 KiB
    float* pd     = (float*)(ws + 2 * 1024 * 1024 + 32 * 1024);   // 16 KiB

    k_prep<<<N_PAIR / 4, 256, 0, stream>>>(zi, zj, zh8, pd, rowsum, (float*)d_out);
    dim3 grid(64 / NX, 128);
    k_simsum<<<grid, 512, 0, stream>>>(zh8, rowsum);
    k_loss<<<N_ROW / 256, 256, 0, stream>>>(rowsum, pd, (float*)d_out);
}